// Round 7
// baseline (416.192 us; speedup 1.0000x reference)
//
#include <hip/hip_runtime.h>
#include <hip/hip_bf16.h>

typedef __attribute__((ext_vector_type(8))) short bf16x8;
typedef __attribute__((ext_vector_type(16))) float f32x16;
typedef __attribute__((ext_vector_type(4))) unsigned short us4;

#define AS1 __attribute__((address_space(1)))
#define AS3 __attribute__((address_space(3)))

__device__ __forceinline__ unsigned short f2bf(float f) {
  unsigned u = __float_as_uint(f);
  u += 0x7fff + ((u >> 16) & 1);   // RNE
  return (unsigned short)(u >> 16);
}

__device__ __forceinline__ void gload_lds16(const void* g, void* l) {
  __builtin_amdgcn_global_load_lds((const AS1 unsigned int*)g,
                                   (AS3 unsigned int*)l, 16, 0, 0);
}

// ---------------------------------------------------------------------------
// C[M,N] = scale * (A[M,K] @ Bt[N,K]^T) + bias.  A,Bt bf16 row-major,
// C fp32 or bf16(ushort). Block tile 128 x (NJ*64), BK=32, 256 thr = 4 waves
// (2x2), wave tile 64 x (NJ*32) of 32x32x16 MFMA.
// A: staged via global_load_lds into double-buffered LDS (XOR chunk swizzle,
//    zero bank conflicts — verified round 4).
// B: NOT in LDS. The 32x32x16 B-operand layout (lane l: n=l&31, k-chunk by
//    l>>5) loads directly from Bt with one global_load_dwordx4 per fragment;
//    L1 serves the 2x cross-wave redundancy. B registers double-buffered
//    across a 2x-unrolled K-loop (load k+32 after barrier, consume k).
//    This halves LDS traffic — the round-4..6 MfmaUtil=30% wall.
// MODE 0: normal output [bz][M][ldc] (+bz*sC).
// MODE 1: fused-QKV de-interleave: per-32-col granule, piece = gcol>>10;
//   pieces 0,1 (Q,K) -> C + piece*sC, compact [8192][1024];
//   piece 2 (V) -> written TRANSPOSED to Vt[b][d][2048] (b = row>>11).
// ---------------------------------------------------------------------------
template <typename OutT, bool BIAS, int MODE, int NJ>
__global__ __launch_bounds__(256, 2) void gemm_bt(
    const unsigned short* __restrict__ A,
    const unsigned short* __restrict__ Bt,
    OutT* __restrict__ C,
    unsigned short* __restrict__ Vt,
    const float* __restrict__ bias,
    int Kd, int lda, int ldb, int ldc,
    long sA, long sB, long sC,
    float scale) {
  constexpr int BN = NJ * 64;        // block N width
  __shared__ unsigned short lds[2][128 * 32];

  const int bz = blockIdx.z;
  A  += (size_t)bz * sA + (size_t)blockIdx.x * 128 * lda;
  Bt += (size_t)bz * sB + (size_t)blockIdx.y * BN * ldb;

  const int tid  = threadIdx.x;
  const int wave = tid >> 6;
  const int lane = tid & 63;
  const int wm   = (wave >> 1) * 64;         // wave row offset
  const int wn   = (wave & 1) * (NJ * 32);   // wave col offset
  const int l32  = lane & 31;
  const int half = lane >> 5;
  // stage-side swizzle: this lane fetches global chunk cg/8 of its row
  const int cg   = ((lane & 3) ^ ((lane >> 2) & 3) ^ (lane >> 4)) * 8;
  // read-side: LDS chunk for global chunk (2h+half) at rows == l32 (mod 16)
  const int pswz = (l32 & 3) ^ ((l32 >> 2) & 3);

  // per-lane B row pointer (B-operand layout direct from global)
  const unsigned short* Bp = Bt + (size_t)(wn + l32) * ldb + 8 * half;

  auto stageA = [&](int k0, int b) {
#pragma unroll
    for (int j = 0; j < 2; ++j) {
      const int s = wave + 4 * j;            // slot (wave-uniform)
      const int r = s * 16 + (lane >> 2);    // A row
      gload_lds16(A + (size_t)r * lda + k0 + cg, (char*)&lds[b][0] + s * 1024);
    }
  };
  auto loadB = [&](int k0, bf16x8 (&b)[NJ][2]) {
#pragma unroll
    for (int u = 0; u < NJ; ++u)
#pragma unroll
      for (int h = 0; h < 2; ++h)
        b[u][h] = *(const bf16x8*)(Bp + (size_t)u * 32 * ldb + k0 + 16 * h);
  };

  f32x16 acc[2][NJ] = {};

  auto compute = [&](int b, bf16x8 (&bf)[NJ][2]) {
    const unsigned short* base = &lds[b][0];
    bf16x8 af[2][2];
#pragma unroll
    for (int t = 0; t < 2; ++t)
#pragma unroll
      for (int h = 0; h < 2; ++h) {
        const int p = ((2 * h + half) ^ pswz) * 8;
        af[t][h] = *(const bf16x8*)&base[(wm + t * 32 + l32) * 32 + p];
      }
#pragma unroll
    for (int t = 0; t < 2; ++t)
#pragma unroll
      for (int u = 0; u < NJ; ++u) {
        acc[t][u] = __builtin_amdgcn_mfma_f32_32x32x16_bf16(af[t][0], bf[u][0], acc[t][u], 0, 0, 0);
        acc[t][u] = __builtin_amdgcn_mfma_f32_32x32x16_bf16(af[t][1], bf[u][1], acc[t][u], 0, 0, 0);
      }
  };

  bf16x8 b0[NJ][2], b1[NJ][2];
  stageA(0, 0);
  loadB(0, b0);
  for (int k0 = 0; k0 < Kd; k0 += 64) {      // Kd is a multiple of 64
    __syncthreads();                         // lds[0] (A[k0]) ready
    if (k0 + 32 < Kd) { stageA(k0 + 32, 1); loadB(k0 + 32, b1); }
    compute(0, b0);
    __syncthreads();                         // lds[1] (A[k0+32]) ready
    if (k0 + 64 < Kd) { stageA(k0 + 64, 0); loadB(k0 + 64, b0); }
    compute(1, b1);
  }

  const int row0 = blockIdx.x * 128 + wm;
  const int colb = blockIdx.y * BN;

  if constexpr (MODE == 1) {
#pragma unroll
    for (int t = 0; t < 2; ++t) {
#pragma unroll
      for (int u = 0; u < NJ; ++u) {
        const int gcol  = colb + wn + u * 32;   // multiple of 32
        const int piece = gcol >> 10;
        const float bv  = BIAS ? bias[gcol + l32] : 0.0f;
        if (piece < 2) {
          OutT* dst = C + (size_t)piece * sC;
          const int col = (gcol & 1023) + l32;
#pragma unroll
          for (int r = 0; r < 16; ++r) {
            const int row = row0 + t * 32 + (r & 3) + 8 * (r >> 2) + 4 * half;
            dst[(size_t)row * ldc + col] = (OutT)f2bf(acc[t][u][r] * scale + bv);
          }
        } else {
          // V piece: write transposed Vt[b][d][2048]
          const int d = (gcol & 1023) + l32;
          const int b = row0 >> 11;
          const int sbase = (row0 & 2047) + t * 32 + 4 * half;
#pragma unroll
          for (int g = 0; g < 4; ++g) {
            const int s0 = sbase + 8 * g;
            us4 pk;
            pk.x = f2bf(acc[t][u][4 * g + 0] * scale + bv);
            pk.y = f2bf(acc[t][u][4 * g + 1] * scale + bv);
            pk.z = f2bf(acc[t][u][4 * g + 2] * scale + bv);
            pk.w = f2bf(acc[t][u][4 * g + 3] * scale + bv);
            *(us4*)&Vt[((size_t)b << 21) + (size_t)d * 2048 + s0] = pk;
          }
        }
      }
    }
  } else {
    C += (size_t)bz * sC;
    const int col0 = colb + wn;
#pragma unroll
    for (int t = 0; t < 2; ++t) {
#pragma unroll
      for (int u = 0; u < NJ; ++u) {
        const int col = col0 + u * 32 + l32;
        const float bv = BIAS ? bias[col0 + u * 32 + l32] : 0.0f;
#pragma unroll
        for (int r = 0; r < 16; ++r) {
          const int row = row0 + t * 32 + (r & 3) + 8 * (r >> 2) + 4 * half;
          const float v = acc[t][u][r] * scale + bv;
          if constexpr (sizeof(OutT) == 4)
            C[(size_t)row * ldc + col] = v;
          else
            C[(size_t)row * ldc + col] = (OutT)f2bf(v);
        }
      }
    }
  }
}

// fp32 -> bf16 flat convert (4 elems/thread)
__global__ void cvt_x(const float* __restrict__ in, unsigned short* __restrict__ out, int n4) {
  const int i = blockIdx.x * blockDim.x + threadIdx.x;
  if (i < n4) {
    const float4 v = ((const float4*)in)[i];
    uint2 o;
    o.x = (unsigned)f2bf(v.x) | ((unsigned)f2bf(v.y) << 16);
    o.y = (unsigned)f2bf(v.z) | ((unsigned)f2bf(v.w) << 16);
    ((uint2*)out)[i] = o;
  }
}

// All 4 weight matrices (1024x1024 fp32) -> bf16 transposed, one launch.
__global__ void cvtT_w4(const float* __restrict__ Wq, const float* __restrict__ Wk,
                        const float* __restrict__ Wv, const float* __restrict__ Wo,
                        unsigned short* __restrict__ Wqkvb, unsigned short* __restrict__ Wob) {
  __shared__ unsigned short tile[64][65];
  const int z = blockIdx.z;
  const float* in = (z == 0) ? Wq : (z == 1) ? Wk : (z == 2) ? Wv : Wo;
  unsigned short* out = (z == 3) ? Wob : Wqkvb + (size_t)z * 1024 * 1024;
  const int r0 = blockIdx.y * 64, c0 = blockIdx.x * 64;
  for (int i = threadIdx.y; i < 64; i += 4)
    tile[i][threadIdx.x] = f2bf(in[(size_t)(r0 + i) * 1024 + c0 + threadIdx.x]);
  __syncthreads();
  for (int i = threadIdx.y; i < 64; i += 4)
    out[(size_t)(c0 + i) * 1024 + r0 + threadIdx.x] = tile[threadIdx.x][i];
}

// concat bq|bk|bv into bqkv
__global__ void concat_bias(const float* __restrict__ bq, const float* __restrict__ bk,
                            const float* __restrict__ bv, float* __restrict__ dst) {
  const int z = blockIdx.x;
  const float* src = (z == 0) ? bq : (z == 1) ? bk : bv;
  const int i = threadIdx.x;
  ((float4*)(dst + z * 1024))[i] = ((const float4*)src)[i];
}

// One block per row of 2048 bf16 scores; softmax in fp32, bf16 in place.
__global__ __launch_bounds__(256) void softmax_bf16(unsigned short* __restrict__ scores) {
  unsigned short* p = scores + (size_t)blockIdx.x * 2048;
  const int t = threadIdx.x;
  uint4 raw = ((const uint4*)p)[t];
  float v[8];
  v[0] = __uint_as_float(raw.x << 16); v[1] = __uint_as_float(raw.x & 0xffff0000u);
  v[2] = __uint_as_float(raw.y << 16); v[3] = __uint_as_float(raw.y & 0xffff0000u);
  v[4] = __uint_as_float(raw.z << 16); v[5] = __uint_as_float(raw.z & 0xffff0000u);
  v[6] = __uint_as_float(raw.w << 16); v[7] = __uint_as_float(raw.w & 0xffff0000u);

  float m = v[0];
#pragma unroll
  for (int i = 1; i < 8; ++i) m = fmaxf(m, v[i]);
#pragma unroll
  for (int off = 32; off; off >>= 1) m = fmaxf(m, __shfl_xor(m, off, 64));

  __shared__ float red[4];
  __shared__ float bcast[2];
  const int wave = t >> 6, lane = t & 63;
  if (lane == 0) red[wave] = m;
  __syncthreads();
  if (t == 0) bcast[0] = fmaxf(fmaxf(red[0], red[1]), fmaxf(red[2], red[3]));
  __syncthreads();
  m = bcast[0];

  float s = 0.f;
#pragma unroll
  for (int i = 0; i < 8; ++i) { v[i] = __expf(v[i] - m); s += v[i]; }
#pragma unroll
  for (int off = 32; off; off >>= 1) s += __shfl_xor(s, off, 64);
  if (lane == 0) red[wave] = s;
  __syncthreads();
  if (t == 0) bcast[1] = red[0] + red[1] + red[2] + red[3];
  __syncthreads();
  const float inv = 1.0f / bcast[1];

  uint4 ov;
  ov.x = (unsigned)f2bf(v[0] * inv) | ((unsigned)f2bf(v[1] * inv) << 16);
  ov.y = (unsigned)f2bf(v[2] * inv) | ((unsigned)f2bf(v[3] * inv) << 16);
  ov.z = (unsigned)f2bf(v[4] * inv) | ((unsigned)f2bf(v[5] * inv) << 16);
  ov.w = (unsigned)f2bf(v[6] * inv) | ((unsigned)f2bf(v[7] * inv) << 16);
  ((uint4*)p)[t] = ov;
}

// ---------------------------------------------------------------------------
extern "C" void kernel_launch(void* const* d_in, const int* in_sizes, int n_in,
                              void* d_out, int out_size, void* d_ws, size_t ws_size,
                              hipStream_t stream) {
  const float* x  = (const float*)d_in[0];
  const float* Wq = (const float*)d_in[1];
  const float* bq = (const float*)d_in[2];
  const float* Wk = (const float*)d_in[3];
  const float* bk = (const float*)d_in[4];
  const float* Wv = (const float*)d_in[5];
  const float* bv = (const float*)d_in[6];
  const float* Wo = (const float*)d_in[7];
  const float* bo = (const float*)d_in[8];
  float* out = (float*)d_out;

  char* ws = (char*)d_ws;
  size_t off = 0;
  auto alloc = [&](size_t bytes) { char* p = ws + off; off += (bytes + 255) & ~255UL; return p; };
  unsigned short* xb    = (unsigned short*)alloc(8192UL * 1024 * 2);     // 16 MiB
  unsigned short* Wqkvb = (unsigned short*)alloc(3072UL * 1024 * 2);     // 6 MiB
  unsigned short* Wob   = (unsigned short*)alloc(1024UL * 1024 * 2);     // 2 MiB
  float*          bqkv  = (float*)alloc(3072UL * 4);
  unsigned short* Qb    = (unsigned short*)alloc(8192UL * 1024 * 2);     // 16 MiB (piece 0)
  unsigned short* Kb    = (unsigned short*)alloc(8192UL * 1024 * 2);     // 16 MiB (piece 1)
  unsigned short* Vtb   = (unsigned short*)alloc(4UL * 1024 * 2048 * 2); // 16 MiB [b][d][s]
  unsigned short* attn  = (unsigned short*)alloc(8192UL * 2048 * 2);     // 32 MiB bf16 scores
  unsigned short* ctxb  = (unsigned short*)alloc(8192UL * 1024 * 2);     // 16 MiB

  const dim3 blk(256);

  // input convert + all weight transposes + bias concat
  cvt_x<<<2097152 / 256, 256, 0, stream>>>(x, xb, 2097152);
  cvtT_w4<<<dim3(16, 16, 4), dim3(64, 4), 0, stream>>>(Wq, Wk, Wv, Wo, Wqkvb, Wob);
  concat_bias<<<3, 256, 0, stream>>>(bq, bk, bv, bqkv);

  // fused QKV projection (NJ=3: 128x192 tiles, grid 1024 = 2 even rounds),
  // Q,K compact + V written transposed to Vtb.
  gemm_bt<unsigned short, true, 1, 3><<<dim3(64, 16, 1), blk, 0, stream>>>(
      xb, Wqkvb, Qb, Vtb, bqkv, 1024, 1024, 1024, 1024, 0, 0, 8192L * 1024, 1.0f);

  // scores = (Q @ K^T) / 32 -> bf16, per batch (NJ=4, grid 512 = 1 round)
  gemm_bt<unsigned short, false, 0, 4><<<dim3(16, 8, 4), blk, 0, stream>>>(
      Qb, Kb, attn, nullptr, nullptr, 1024, 1024, 1024, 2048,
      2048L * 1024, 2048L * 1024, 2048L * 2048, 0.03125f);

  // softmax rows in place (bf16, dense ld=2048)
  softmax_bf16<<<8192, 256, 0, stream>>>(attn);

  // ctx = attn @ V  (attn lda=2048, Vt is Bt layout) (NJ=2)
  gemm_bt<unsigned short, false, 0, 2><<<dim3(16, 8, 4), blk, 0, stream>>>(
      attn, Vtb, ctxb, nullptr, nullptr, 2048, 2048, 2048, 1024,
      2048L * 2048, 1024L * 2048, 2048L * 1024, 1.0f);

  // out = ctx @ Wo + bo (fp32 out) (NJ=2)
  gemm_bt<float, true, 0, 2><<<dim3(64, 8, 1), blk, 0, stream>>>(
      ctxb, Wob, out, nullptr, bo, 1024, 1024, 1024, 1024, 0, 0, 0, 1.0f);
}

// Round 8
// 301.841 us; speedup vs baseline: 1.3788x; 1.3788x over previous
//
#include <hip/hip_runtime.h>
#include <hip/hip_bf16.h>

typedef __attribute__((ext_vector_type(8))) short bf16x8;
typedef __attribute__((ext_vector_type(16))) float f32x16;
typedef __attribute__((ext_vector_type(4))) unsigned short us4;

#define AS1 __attribute__((address_space(1)))
#define AS3 __attribute__((address_space(3)))

__device__ __forceinline__ unsigned short f2bf(float f) {
  unsigned u = __float_as_uint(f);
  u += 0x7fff + ((u >> 16) & 1);   // RNE
  return (unsigned short)(u >> 16);
}

__device__ __forceinline__ void gload_lds16(const void* g, void* l) {
  __builtin_amdgcn_global_load_lds((const AS1 unsigned int*)g,
                                   (AS3 unsigned int*)l, 16, 0, 0);
}

// ---------------------------------------------------------------------------
// C[M,N] = scale * (A[M,K] @ Bt[N,K]^T) + bias.  A,Bt bf16 row-major,
// C fp32 or bf16(ushort). Block tile (2*MT*32) x (2*NT*32), BK=32,
// 256 thr = 4 waves in 2x2; wave tile (MT*32) x (NT*32) of 32x32x16 MFMA.
// Both A and B staged via global_load_lds into double-buffered LDS with
// XOR chunk swizzle (zero bank conflicts, verified round 4). Round-7's
// B-from-global scatter regressed (64 lines/instr) — reverted.
// Big MT cuts LDS bytes per MFMA: reads 2(MT+NT) b128 per 2*MT*NT MFMAs.
// MODE 0: normal output [bz][M][ldc] (+bz*sC).
// MODE 1: fused-QKV de-interleave: per-32-col granule, piece = gcol>>10;
//   pieces 0,1 (Q,K) -> C + piece*sC, compact [8192][1024];
//   piece 2 (V) -> written TRANSPOSED to Vt[b][d][2048] (b = row>>11).
// ---------------------------------------------------------------------------
template <typename OutT, bool BIAS, int MODE, int MT, int NT, int MINW>
__global__ __launch_bounds__(256, MINW) void gemm_bt(
    const unsigned short* __restrict__ A,
    const unsigned short* __restrict__ Bt,
    OutT* __restrict__ C,
    unsigned short* __restrict__ Vt,
    const float* __restrict__ bias,
    int Kd, int lda, int ldb, int ldc,
    long sA, long sB, long sC,
    float scale) {
  constexpr int BM    = 2 * MT * 32;
  constexpr int BN    = 2 * NT * 32;
  constexpr int ROWS  = BM + BN;     // staged rows per k-tile (A then B)
  constexpr int SLOTS = ROWS / 16;   // 1-KB staging slots (16 rows each)
  static_assert(SLOTS % 4 == 0, "stage loop needs SLOTS%4==0");
  __shared__ unsigned short lds[2][ROWS * 32];

  const int bz = blockIdx.z;
  A  += (size_t)bz * sA + (size_t)blockIdx.x * BM * lda;
  Bt += (size_t)bz * sB + (size_t)blockIdx.y * BN * ldb;

  const int tid  = threadIdx.x;
  const int wave = tid >> 6;
  const int lane = tid & 63;
  const int wm   = (wave >> 1) * (MT * 32);  // wave row offset
  const int wn   = (wave & 1) * (NT * 32);   // wave col offset
  const int l32  = lane & 31;
  const int half = lane >> 5;
  // stage-side swizzle: this lane fetches global chunk cg/8 of its row
  const int cg   = ((lane & 3) ^ ((lane >> 2) & 3) ^ (lane >> 4)) * 8;
  // read-side: LDS chunk for global chunk (2h+half) at rows == l32 (mod 16)
  const int pswz = (l32 & 3) ^ ((l32 >> 2) & 3);

  auto stage = [&](int k0, int b) {
#pragma unroll
    for (int j = 0; j < SLOTS / 4; ++j) {
      const int s = wave + 4 * j;            // slot (wave-uniform)
      const int r = s * 16 + (lane >> 2);    // row in concat(A,B) space
      const unsigned short* src = (s < BM / 16) ? (A + (size_t)r * lda)
                                                : (Bt + (size_t)(r - BM) * ldb);
      gload_lds16(src + k0 + cg, (char*)&lds[b][0] + s * 1024);
    }
  };

  f32x16 acc[MT][NT] = {};

  stage(0, 0);
  int cur = 0;
  for (int k0 = 0; k0 < Kd; k0 += 32) {
    __syncthreads();                         // drains prefetch of lds[cur]
    if (k0 + 32 < Kd) stage(k0 + 32, cur ^ 1);

    const unsigned short* base = &lds[cur][0];
    bf16x8 af[MT][2], bfr[NT][2];
#pragma unroll
    for (int t = 0; t < MT; ++t)
#pragma unroll
      for (int h = 0; h < 2; ++h) {
        const int p = ((2 * h + half) ^ pswz) * 8;
        af[t][h] = *(const bf16x8*)&base[(wm + t * 32 + l32) * 32 + p];
      }
#pragma unroll
    for (int u = 0; u < NT; ++u)
#pragma unroll
      for (int h = 0; h < 2; ++h) {
        const int p = ((2 * h + half) ^ pswz) * 8;
        bfr[u][h] = *(const bf16x8*)&base[(BM + wn + u * 32 + l32) * 32 + p];
      }
#pragma unroll
    for (int t = 0; t < MT; ++t)
#pragma unroll
      for (int u = 0; u < NT; ++u) {
        acc[t][u] = __builtin_amdgcn_mfma_f32_32x32x16_bf16(af[t][0], bfr[u][0], acc[t][u], 0, 0, 0);
        acc[t][u] = __builtin_amdgcn_mfma_f32_32x32x16_bf16(af[t][1], bfr[u][1], acc[t][u], 0, 0, 0);
      }
    cur ^= 1;
  }

  const int row0 = blockIdx.x * BM + wm;
  const int colb = blockIdx.y * BN;

  if constexpr (MODE == 1) {
#pragma unroll
    for (int t = 0; t < MT; ++t) {
#pragma unroll
      for (int u = 0; u < NT; ++u) {
        const int gcol  = colb + wn + u * 32;   // multiple of 32
        const int piece = gcol >> 10;
        const float bv  = BIAS ? bias[gcol + l32] : 0.0f;
        if (piece < 2) {
          OutT* dst = C + (size_t)piece * sC;
          const int col = (gcol & 1023) + l32;
#pragma unroll
          for (int r = 0; r < 16; ++r) {
            const int row = row0 + t * 32 + (r & 3) + 8 * (r >> 2) + 4 * half;
            dst[(size_t)row * ldc + col] = (OutT)f2bf(acc[t][u][r] * scale + bv);
          }
        } else {
          // V piece: write transposed Vt[b][d][2048]
          const int d = (gcol & 1023) + l32;
          const int b = row0 >> 11;
          const int sbase = (row0 & 2047) + t * 32 + 4 * half;
#pragma unroll
          for (int g = 0; g < 4; ++g) {
            const int s0 = sbase + 8 * g;
            us4 pk;
            pk.x = f2bf(acc[t][u][4 * g + 0] * scale + bv);
            pk.y = f2bf(acc[t][u][4 * g + 1] * scale + bv);
            pk.z = f2bf(acc[t][u][4 * g + 2] * scale + bv);
            pk.w = f2bf(acc[t][u][4 * g + 3] * scale + bv);
            *(us4*)&Vt[((size_t)b << 21) + (size_t)d * 2048 + s0] = pk;
          }
        }
      }
    }
  } else {
    C += (size_t)bz * sC;
    const int col0 = colb + wn;
#pragma unroll
    for (int t = 0; t < MT; ++t) {
#pragma unroll
      for (int u = 0; u < NT; ++u) {
        const int col = col0 + u * 32 + l32;
        const float bv = BIAS ? bias[col0 + u * 32 + l32] : 0.0f;
#pragma unroll
        for (int r = 0; r < 16; ++r) {
          const int row = row0 + t * 32 + (r & 3) + 8 * (r >> 2) + 4 * half;
          const float v = acc[t][u][r] * scale + bv;
          if constexpr (sizeof(OutT) == 4)
            C[(size_t)row * ldc + col] = v;
          else
            C[(size_t)row * ldc + col] = (OutT)f2bf(v);
        }
      }
    }
  }
}

// fp32 -> bf16 flat convert (4 elems/thread)
__global__ void cvt_x(const float* __restrict__ in, unsigned short* __restrict__ out, int n4) {
  const int i = blockIdx.x * blockDim.x + threadIdx.x;
  if (i < n4) {
    const float4 v = ((const float4*)in)[i];
    uint2 o;
    o.x = (unsigned)f2bf(v.x) | ((unsigned)f2bf(v.y) << 16);
    o.y = (unsigned)f2bf(v.z) | ((unsigned)f2bf(v.w) << 16);
    ((uint2*)out)[i] = o;
  }
}

// All 4 weight matrices (1024x1024 fp32) -> bf16 transposed, one launch.
__global__ void cvtT_w4(const float* __restrict__ Wq, const float* __restrict__ Wk,
                        const float* __restrict__ Wv, const float* __restrict__ Wo,
                        unsigned short* __restrict__ Wqkvb, unsigned short* __restrict__ Wob) {
  __shared__ unsigned short tile[64][65];
  const int z = blockIdx.z;
  const float* in = (z == 0) ? Wq : (z == 1) ? Wk : (z == 2) ? Wv : Wo;
  unsigned short* out = (z == 3) ? Wob : Wqkvb + (size_t)z * 1024 * 1024;
  const int r0 = blockIdx.y * 64, c0 = blockIdx.x * 64;
  for (int i = threadIdx.y; i < 64; i += 4)
    tile[i][threadIdx.x] = f2bf(in[(size_t)(r0 + i) * 1024 + c0 + threadIdx.x]);
  __syncthreads();
  for (int i = threadIdx.y; i < 64; i += 4)
    out[(size_t)(c0 + i) * 1024 + r0 + threadIdx.x] = tile[threadIdx.x][i];
}

// concat bq|bk|bv into bqkv
__global__ void concat_bias(const float* __restrict__ bq, const float* __restrict__ bk,
                            const float* __restrict__ bv, float* __restrict__ dst) {
  const int z = blockIdx.x;
  const float* src = (z == 0) ? bq : (z == 1) ? bk : bv;
  const int i = threadIdx.x;
  ((float4*)(dst + z * 1024))[i] = ((const float4*)src)[i];
}

// One block per row of 2048 bf16 scores; softmax in fp32, bf16 in place.
__global__ __launch_bounds__(256) void softmax_bf16(unsigned short* __restrict__ scores) {
  unsigned short* p = scores + (size_t)blockIdx.x * 2048;
  const int t = threadIdx.x;
  uint4 raw = ((const uint4*)p)[t];
  float v[8];
  v[0] = __uint_as_float(raw.x << 16); v[1] = __uint_as_float(raw.x & 0xffff0000u);
  v[2] = __uint_as_float(raw.y << 16); v[3] = __uint_as_float(raw.y & 0xffff0000u);
  v[4] = __uint_as_float(raw.z << 16); v[5] = __uint_as_float(raw.z & 0xffff0000u);
  v[6] = __uint_as_float(raw.w << 16); v[7] = __uint_as_float(raw.w & 0xffff0000u);

  float m = v[0];
#pragma unroll
  for (int i = 1; i < 8; ++i) m = fmaxf(m, v[i]);
#pragma unroll
  for (int off = 32; off; off >>= 1) m = fmaxf(m, __shfl_xor(m, off, 64));

  __shared__ float red[4];
  __shared__ float bcast[2];
  const int wave = t >> 6, lane = t & 63;
  if (lane == 0) red[wave] = m;
  __syncthreads();
  if (t == 0) bcast[0] = fmaxf(fmaxf(red[0], red[1]), fmaxf(red[2], red[3]));
  __syncthreads();
  m = bcast[0];

  float s = 0.f;
#pragma unroll
  for (int i = 0; i < 8; ++i) { v[i] = __expf(v[i] - m); s += v[i]; }
#pragma unroll
  for (int off = 32; off; off >>= 1) s += __shfl_xor(s, off, 64);
  if (lane == 0) red[wave] = s;
  __syncthreads();
  if (t == 0) bcast[1] = red[0] + red[1] + red[2] + red[3];
  __syncthreads();
  const float inv = 1.0f / bcast[1];

  uint4 ov;
  ov.x = (unsigned)f2bf(v[0] * inv) | ((unsigned)f2bf(v[1] * inv) << 16);
  ov.y = (unsigned)f2bf(v[2] * inv) | ((unsigned)f2bf(v[3] * inv) << 16);
  ov.z = (unsigned)f2bf(v[4] * inv) | ((unsigned)f2bf(v[5] * inv) << 16);
  ov.w = (unsigned)f2bf(v[6] * inv) | ((unsigned)f2bf(v[7] * inv) << 16);
  ((uint4*)p)[t] = ov;
}

// ---------------------------------------------------------------------------
extern "C" void kernel_launch(void* const* d_in, const int* in_sizes, int n_in,
                              void* d_out, int out_size, void* d_ws, size_t ws_size,
                              hipStream_t stream) {
  const float* x  = (const float*)d_in[0];
  const float* Wq = (const float*)d_in[1];
  const float* bq = (const float*)d_in[2];
  const float* Wk = (const float*)d_in[3];
  const float* bk = (const float*)d_in[4];
  const float* Wv = (const float*)d_in[5];
  const float* bv = (const float*)d_in[6];
  const float* Wo = (const float*)d_in[7];
  const float* bo = (const float*)d_in[8];
  float* out = (float*)d_out;

  char* ws = (char*)d_ws;
  size_t off = 0;
  auto alloc = [&](size_t bytes) { char* p = ws + off; off += (bytes + 255) & ~255UL; return p; };
  unsigned short* xb    = (unsigned short*)alloc(8192UL * 1024 * 2);     // 16 MiB
  unsigned short* Wqkvb = (unsigned short*)alloc(3072UL * 1024 * 2);     // 6 MiB
  unsigned short* Wob   = (unsigned short*)alloc(1024UL * 1024 * 2);     // 2 MiB
  float*          bqkv  = (float*)alloc(3072UL * 4);
  unsigned short* Qb    = (unsigned short*)alloc(8192UL * 1024 * 2);     // 16 MiB (piece 0)
  unsigned short* Kb    = (unsigned short*)alloc(8192UL * 1024 * 2);     // 16 MiB (piece 1)
  unsigned short* Vtb   = (unsigned short*)alloc(4UL * 1024 * 2048 * 2); // 16 MiB [b][d][s]
  unsigned short* attn  = (unsigned short*)alloc(8192UL * 2048 * 2);     // 32 MiB bf16 scores
  unsigned short* ctxb  = (unsigned short*)alloc(8192UL * 1024 * 2);     // 16 MiB

  const dim3 blk(256);

  // input convert + all weight transposes + bias concat
  cvt_x<<<2097152 / 256, 256, 0, stream>>>(x, xb, 2097152);
  cvtT_w4<<<dim3(16, 16, 4), dim3(64, 4), 0, stream>>>(Wq, Wk, Wv, Wo, Wqkvb, Wob);
  concat_bias<<<3, 256, 0, stream>>>(bq, bk, bv, bqkv);

  // fused QKV projection: 256x192 tiles (MT=4,NT=3), grid 512 = 2 exact
  // rounds at 1 block/CU. Q,K compact + V written transposed to Vtb.
  gemm_bt<unsigned short, true, 1, 4, 3, 1><<<dim3(32, 16, 1), blk, 0, stream>>>(
      xb, Wqkvb, Qb, Vtb, bqkv, 1024, 1024, 1024, 1024, 0, 0, 8192L * 1024, 1.0f);

  // scores = (Q @ K^T) / 32 -> bf16: 256x256 tiles (MT=4,NT=4), grid 256.
  gemm_bt<unsigned short, false, 0, 4, 4, 1><<<dim3(8, 8, 4), blk, 0, stream>>>(
      Qb, Kb, attn, nullptr, nullptr, 1024, 1024, 1024, 2048,
      2048L * 1024, 2048L * 1024, 2048L * 2048, 0.03125f);

  // softmax rows in place (bf16, dense ld=2048)
  softmax_bf16<<<8192, 256, 0, stream>>>(attn);

  // ctx = attn @ V: 256x128 tiles (MT=4,NT=2), 2 blocks/CU.
  gemm_bt<unsigned short, false, 0, 4, 2, 2><<<dim3(8, 8, 4), blk, 0, stream>>>(
      attn, Vtb, ctxb, nullptr, nullptr, 2048, 2048, 2048, 1024,
      2048L * 2048, 1024L * 2048, 2048L * 1024, 1.0f);

  // out = ctx @ Wo + bo (fp32 out): 256x128 tiles (MT=4,NT=2).
  gemm_bt<float, true, 0, 4, 2, 2><<<dim3(32, 8, 1), blk, 0, stream>>>(
      ctxb, Wob, out, nullptr, bo, 1024, 1024, 1024, 1024, 0, 0, 0, 1.0f);
}